// Round 5
// baseline (685.567 us; speedup 1.0000x reference)
//
#include <hip/hip_runtime.h>

#define FIN 128
#define FHID 32
#define FOUT 64
#define MAXDEG 10

// edge_index arrives as int32 (harness converts integer inputs to int):
// layout [2, E] flat: src = ei[e], dst = ei[E + e].

__device__ __forceinline__ float bf2f(unsigned short u) {
    union { unsigned int i; float f; } c; c.i = ((unsigned int)u) << 16; return c.f;
}
__device__ __forceinline__ unsigned short f2bf(float f) {
    union { float f; unsigned int i; } c; c.f = f;
    unsigned int r = c.i + 0x7FFF + ((c.i >> 16) & 1);   // round-nearest-even
    return (unsigned short)(r >> 16);
}

// ---------- CSR build ----------

__global__ __launch_bounds__(256) void k_count(const int* __restrict__ ei, int E, int N,
                                               int* __restrict__ deg) {
    int e = blockIdx.x * 256 + threadIdx.x;
    if (e >= E) return;
    int d = ei[E + e];
    if ((unsigned)d < (unsigned)N) atomicAdd(deg + d, 1);
}

__global__ __launch_bounds__(256) void k_blocksum(const int* __restrict__ deg, int N,
                                                  int* __restrict__ partial) {
    __shared__ int tmp[256];
    int t = threadIdx.x;
    int i = blockIdx.x * 256 + t;
    tmp[t] = (i < N) ? deg[i] : 0;
    __syncthreads();
    for (int off = 128; off > 0; off >>= 1) {
        if (t < off) tmp[t] += tmp[t + off];
        __syncthreads();
    }
    if (t == 0) partial[blockIdx.x] = tmp[0];
}

// single-block exclusive scan of partial[0..NB) -> offsets   (requires NB <= 1024)
__global__ __launch_bounds__(1024) void k_scanpartial(const int* __restrict__ partial, int NB,
                                                      int* __restrict__ offsets) {
    __shared__ int tmp[1024];
    int t = threadIdx.x;
    int v = (t < NB) ? partial[t] : 0;
    tmp[t] = v;
    __syncthreads();
    for (int off = 1; off < 1024; off <<= 1) {
        int a = (t >= off) ? tmp[t - off] : 0;
        __syncthreads();
        tmp[t] += a;
        __syncthreads();
    }
    if (t < NB) offsets[t] = tmp[t] - v;
}

__global__ __launch_bounds__(256) void k_scandeg(const int* __restrict__ deg, int N,
                                                 const int* __restrict__ offsets,
                                                 int* __restrict__ cursor) {
    __shared__ int tmp[256];
    int t = threadIdx.x;
    int i = blockIdx.x * 256 + t;
    int v = (i < N) ? deg[i] : 0;
    tmp[t] = v;
    __syncthreads();
    for (int off = 1; off < 256; off <<= 1) {
        int a = (t >= off) ? tmp[t - off] : 0;
        __syncthreads();
        tmp[t] += a;
        __syncthreads();
    }
    if (i < N) cursor[i] = offsets[blockIdx.x] + tmp[t] - v;
}

__global__ __launch_bounds__(256) void k_fill(const int* __restrict__ ei, int E, int N,
                                              int* __restrict__ cursor, int* __restrict__ adj) {
    int e = blockIdx.x * 256 + threadIdx.x;
    if (e >= E) return;
    int s = ei[e];
    int d = ei[E + e];
    if ((unsigned)s >= (unsigned)N || (unsigned)d >= (unsigned)N) return;
    int pos = atomicAdd(cursor + d, 1);   // cursor ends at row end = rowstart + deg
    if ((unsigned)pos < (unsigned)E) adj[pos] = s;
}

// ---------- pre1: z10 = x@W1[10] (bf16), r1 = x@Wr1[d_n]+b1 (bf16) ----------
// wave per 4 nodes; lane (u = lane>>5, o = lane&31) covers nodes {q+u, q+u+2}.
// x read as wave-uniform float4 broadcasts; W1[10] loads shared by all 4 nodes.
// NO shfl in the matvec (R4's 151us kernel was ds_bpermute-throughput-bound).
__global__ __launch_bounds__(256) void k_pre1(const float* __restrict__ x,
                                              const int* __restrict__ deg,
                                              const float* __restrict__ W1,
                                              const float* __restrict__ b1,
                                              const float* __restrict__ Wr1,
                                              unsigned short* __restrict__ z10,
                                              unsigned short* __restrict__ r1, int N) {
    int wq = (int)(((long long)blockIdx.x * 256 + threadIdx.x) >> 6);
    int q = wq * 4;
    if (q >= N) return;
    int lane = threadIdx.x & 63;
    int u = lane >> 5;
    int o = lane & 31;
    int n_a = q + u;
    int n_b = q + u + 2;
    int ca = (n_a < N) ? n_a : N - 1;
    int cb = (n_b < N) ? n_b : N - 1;
    int da = min(deg[ca], MAXDEG);
    int db = min(deg[cb], MAXDEG);
    const float* Wz  = W1  + (size_t)MAXDEG * (FIN * FHID) + o;
    const float* Wra = Wr1 + (size_t)da * (FIN * FHID) + o;
    const float* Wrb = Wr1 + (size_t)db * (FIN * FHID) + o;
    const float4* xa4 = (const float4*)(x + (size_t)ca * FIN);
    const float4* xb4 = (const float4*)(x + (size_t)cb * FIN);
    float za = 0.f, zb = 0.f, ra = 0.f, rb = 0.f;
#pragma unroll 4
    for (int f4 = 0; f4 < FIN / 4; ++f4) {
        float4 xa = xa4[f4];
        float4 xb = xb4[f4];
#pragma unroll
        for (int j = 0; j < 4; ++j) {
            int f = f4 * 4 + j;
            float xaj = (j == 0) ? xa.x : (j == 1) ? xa.y : (j == 2) ? xa.z : xa.w;
            float xbj = (j == 0) ? xb.x : (j == 1) ? xb.y : (j == 2) ? xb.z : xb.w;
            float wz = Wz[f * FHID];
            float wa = Wra[f * FHID];
            float wb = Wrb[f * FHID];
            za += xaj * wz;
            zb += xbj * wz;
            ra += xaj * wa;
            rb += xbj * wb;
        }
    }
    if (n_a < N) {
        z10[(size_t)n_a * FHID + o] = f2bf(za);
        r1[(size_t)n_a * FHID + o]  = f2bf(ra + b1[da * FHID + o]);
    }
    if (n_b < N) {
        z10[(size_t)n_b * FHID + o] = f2bf(zb);
        r1[(size_t)n_b * FHID + o]  = f2bf(rb + b1[db * FHID + o]);
    }
}

// ---------- layer1: deg>=10 fast path gathers L2-resident bf16 z10 rows ----------
__global__ __launch_bounds__(256) void k_layer1b(const float* __restrict__ x,
                                                 const unsigned short* __restrict__ z10,
                                                 const unsigned short* __restrict__ r1,
                                                 const int* __restrict__ deg,
                                                 const int* __restrict__ cursor,
                                                 const int* __restrict__ adj,
                                                 const float* __restrict__ W1,
                                                 unsigned short* __restrict__ out1, int N) {
    int wave = (int)(((long long)blockIdx.x * 256 + threadIdx.x) >> 6);
    if (wave >= N) return;
    int n = wave;
    int lane = threadIdx.x & 63;
    int dg = deg[n];
    int e1 = cursor[n];
    int e0 = e1 - dg;
    if (dg >= MAXDEG) {
        // 4 neighbors in flight: group g reads neighbor k; lane l holds features (2l,2l+1)
        int g = lane >> 4, l = lane & 15;
        float2 acc = make_float2(0.f, 0.f);
        for (int k = e0 + g; k < e1; k += 4) {
            int s = adj[k];
            ushort2 uv = *(const ushort2*)(z10 + (size_t)s * FHID + l * 2);
            acc.x += bf2f(uv.x); acc.y += bf2f(uv.y);
        }
        acc.x += __shfl_xor(acc.x, 16); acc.y += __shfl_xor(acc.y, 16);
        acc.x += __shfl_xor(acc.x, 32); acc.y += __shfl_xor(acc.y, 32);
        if (lane < 16) {
            ushort2 rv = *(const ushort2*)(r1 + (size_t)n * FHID + l * 2);
            ushort2 w;
            w.x = f2bf(fmaxf(acc.x + bf2f(rv.x), 0.f));
            w.y = f2bf(fmaxf(acc.y + bf2f(rv.y), 0.f));
            *(ushort2*)(out1 + (size_t)n * FHID + l * 2) = w;
        }
    } else {
        // rare (~4% of nodes): gather raw fp32 x rows, matvec with this node's bucket
        float2 hs = make_float2(0.f, 0.f);
        for (int k = e0; k < e1; ++k) {
            int s = adj[k];
            float2 v = *(const float2*)(x + (size_t)s * FIN + lane * 2);
            hs.x += v.x; hs.y += v.y;
        }
        int o = lane & 31;
        const float* Wp = W1 + (size_t)dg * (FIN * FHID) + o;
        float acc = 0.f;
#pragma unroll
        for (int f = 0; f < FIN; ++f) {
            float hv = __shfl((f & 1) ? hs.y : hs.x, f >> 1);
            acc += hv * Wp[f * FHID];
        }
        if (lane < 32) {
            float rv = bf2f(r1[(size_t)n * FHID + o]);
            out1[(size_t)n * FHID + o] = f2bf(fmaxf(acc + rv, 0.f));
        }
    }
}

// ---------- pre2: p = y@W2[10] (bf16), r2 = y@Wr2[d_n]+b2 (bf16) ----------
// wave per 4 nodes; lane j covers all 64 output cols; W2[10] loads shared by 4 nodes.
__global__ __launch_bounds__(256) void k_pre2(const unsigned short* __restrict__ y,
                                              const int* __restrict__ deg,
                                              const float* __restrict__ W2,
                                              const float* __restrict__ b2,
                                              const float* __restrict__ Wr2,
                                              unsigned short* __restrict__ p,
                                              unsigned short* __restrict__ r2, int N) {
    int wq = (int)(((long long)blockIdx.x * 256 + threadIdx.x) >> 6);
    int q = wq * 4;
    if (q >= N) return;
    int j = threadIdx.x & 63;
    int n[4], d[4];
#pragma unroll
    for (int k = 0; k < 4; ++k) {
        n[k] = (q + k < N) ? q + k : N - 1;
        d[k] = min(deg[n[k]], MAXDEG);
    }
    const float* Wp = W2 + (size_t)MAXDEG * (FHID * FOUT) + j;
    const float* Wr[4];
    float accp[4], accr[4];
#pragma unroll
    for (int k = 0; k < 4; ++k) {
        Wr[k] = Wr2 + (size_t)d[k] * (FHID * FOUT) + j;
        accp[k] = 0.f;
        accr[k] = b2[d[k] * FOUT + j];
    }
#pragma unroll
    for (int c = 0; c < 4; ++c) {           // 8 features per chunk
        uint4 yc[4];
#pragma unroll
        for (int k = 0; k < 4; ++k)
            yc[k] = ((const uint4*)(y + (size_t)n[k] * FHID))[c];
#pragma unroll
        for (int m = 0; m < 8; ++m) {
            int f = c * 8 + m;
            float wv = Wp[f * FOUT];
            float yv[4];
#pragma unroll
            for (int k = 0; k < 4; ++k) {
                unsigned int word = (m >> 1 == 0) ? yc[k].x : (m >> 1 == 1) ? yc[k].y
                                   : (m >> 1 == 2) ? yc[k].z : yc[k].w;
                yv[k] = bf2f((unsigned short)((m & 1) ? (word >> 16) : (word & 0xffff)));
            }
#pragma unroll
            for (int k = 0; k < 4; ++k) {
                accp[k] += yv[k] * wv;
                accr[k] += yv[k] * Wr[k][f * FOUT];
            }
        }
    }
#pragma unroll
    for (int k = 0; k < 4; ++k) {
        if (q + k < N) {
            p[(size_t)n[k] * FOUT + j]  = f2bf(accp[k]);
            r2[(size_t)n[k] * FOUT + j] = f2bf(accr[k]);
        }
    }
}

// ---------- layer2: deg>=10 fast path gathers bf16 p rows; out = sum(p_j) + r2 ----------
__global__ __launch_bounds__(256) void k_layer2b(const unsigned short* __restrict__ p,
                                                 const unsigned short* __restrict__ r2,
                                                 const unsigned short* __restrict__ y,
                                                 const int* __restrict__ deg,
                                                 const int* __restrict__ cursor,
                                                 const int* __restrict__ adj,
                                                 const float* __restrict__ W2,
                                                 float* __restrict__ out, int N) {
    int wave = (int)(((long long)blockIdx.x * 256 + threadIdx.x) >> 6);
    if (wave >= N) return;
    int n = wave;
    int lane = threadIdx.x & 63;
    int dg = deg[n];
    int e1 = cursor[n];
    int e0 = e1 - dg;
    if (dg >= MAXDEG) {
        // 2 neighbors in flight: half g reads neighbor k; lane l holds cols (2l,2l+1)
        int g = lane >> 5, l = lane & 31;
        float2 acc = make_float2(0.f, 0.f);
        for (int k = e0 + g; k < e1; k += 2) {
            int s = adj[k];
            ushort2 uv = *(const ushort2*)(p + (size_t)s * FOUT + l * 2);
            acc.x += bf2f(uv.x); acc.y += bf2f(uv.y);
        }
        acc.x += __shfl_xor(acc.x, 32); acc.y += __shfl_xor(acc.y, 32);
        if (lane < 32) {
            ushort2 rv = *(const ushort2*)(r2 + (size_t)n * FOUT + l * 2);
            float2 ov;
            ov.x = acc.x + bf2f(rv.x);
            ov.y = acc.y + bf2f(rv.y);
            *(float2*)(out + (size_t)n * FOUT + l * 2) = ov;
        }
    } else {
        // rare: gather bf16 y rows (4-way ILP), then 32->64 matvec; r2 has root+bias
        int g = lane >> 4, l = lane & 15;
        float2 h = make_float2(0.f, 0.f);
        for (int k = e0 + g; k < e1; k += 4) {
            int s = adj[k];
            ushort2 uv = *(const ushort2*)(y + (size_t)s * FHID + l * 2);
            h.x += bf2f(uv.x); h.y += bf2f(uv.y);
        }
        h.x += __shfl_xor(h.x, 16); h.y += __shfl_xor(h.y, 16);
        h.x += __shfl_xor(h.x, 32); h.y += __shfl_xor(h.y, 32);
        const float* Wp = W2 + (size_t)dg * (FHID * FOUT) + lane;
        float acc = bf2f(r2[(size_t)n * FOUT + lane]);
#pragma unroll
        for (int f = 0; f < FHID; ++f) {
            float hf = __shfl((f & 1) ? h.y : h.x, f >> 1);
            acc += hf * Wp[f * FOUT];
        }
        out[(size_t)n * FOUT + lane] = acc;
    }
}

extern "C" void kernel_launch(void* const* d_in, const int* in_sizes, int n_in,
                              void* d_out, int out_size, void* d_ws, size_t ws_size,
                              hipStream_t stream) {
    const float* x   = (const float*)d_in[0];
    const int*   ei  = (const int*)d_in[1];   // int32, [2, E] flat
    const float* W1  = (const float*)d_in[2];
    const float* b1  = (const float*)d_in[3];
    const float* Wr1 = (const float*)d_in[4];
    const float* W2  = (const float*)d_in[5];
    const float* b2  = (const float*)d_in[6];
    const float* Wr2 = (const float*)d_in[7];

    int N = in_sizes[0] / FIN;
    int E = in_sizes[1] / 2;
    int NB = (N + 255) / 256;

    char* ws = (char*)d_ws;
    size_t off = 0;
    auto alloc = [&](size_t bytes) {
        void* ptr = ws + off;
        off += (bytes + 511) / 512 * 512;
        return ptr;
    };
    int* deg              = (int*)alloc((size_t)N * sizeof(int));
    int* cursor           = (int*)alloc((size_t)N * sizeof(int));
    int* partial          = (int*)alloc((size_t)NB * sizeof(int));
    int* offsets          = (int*)alloc((size_t)NB * sizeof(int));
    int* adj              = (int*)alloc((size_t)E * sizeof(int));
    unsigned short* z10   = (unsigned short*)alloc((size_t)N * FHID * 2);
    unsigned short* r1    = (unsigned short*)alloc((size_t)N * FHID * 2);
    unsigned short* out1  = (unsigned short*)alloc((size_t)N * FHID * 2);
    unsigned short* p     = (unsigned short*)alloc((size_t)N * FOUT * 2);
    unsigned short* r2    = (unsigned short*)alloc((size_t)N * FOUT * 2);
    // total ~52 MB for N=100K, E=1.6M

    float* out = (float*)d_out;

    hipMemsetAsync(deg, 0, (size_t)N * sizeof(int), stream);

    int eb = (E + 255) / 256;
    k_count<<<eb, 256, 0, stream>>>(ei, E, N, deg);
    k_blocksum<<<NB, 256, 0, stream>>>(deg, N, partial);
    k_scanpartial<<<1, 1024, 0, stream>>>(partial, NB, offsets);
    k_scandeg<<<NB, 256, 0, stream>>>(deg, N, offsets, cursor);
    k_fill<<<eb, 256, 0, stream>>>(ei, E, N, cursor, adj);

    int nb_quad = (N + 15) / 16;  // wave per 4 nodes
    int nb_node = (N + 3) / 4;    // wave per node
    k_pre1<<<nb_quad, 256, 0, stream>>>(x, deg, W1, b1, Wr1, z10, r1, N);
    k_layer1b<<<nb_node, 256, 0, stream>>>(x, z10, r1, deg, cursor, adj, W1, out1, N);
    k_pre2<<<nb_quad, 256, 0, stream>>>(out1, deg, W2, b2, Wr2, p, r2, N);
    k_layer2b<<<nb_node, 256, 0, stream>>>(p, r2, out1, deg, cursor, adj, W2, out, N);
}

// Round 6
// 620.378 us; speedup vs baseline: 1.1051x; 1.1051x over previous
//
#include <hip/hip_runtime.h>

#define FIN 128
#define FHID 32
#define FOUT 64
#define MAXDEG 10

// edge_index arrives as int32 (harness converts integer inputs to int):
// layout [2, E] flat: src = ei[e], dst = ei[E + e].

__device__ __forceinline__ float bf2f(unsigned short u) {
    union { unsigned int i; float f; } c; c.i = ((unsigned int)u) << 16; return c.f;
}
__device__ __forceinline__ unsigned short f2bf(float f) {
    union { float f; unsigned int i; } c; c.f = f;
    unsigned int r = c.i + 0x7FFF + ((c.i >> 16) & 1);   // round-nearest-even
    return (unsigned short)(r >> 16);
}
__device__ __forceinline__ float bflo(unsigned int w) { return bf2f((unsigned short)(w & 0xffff)); }
__device__ __forceinline__ float bfhi(unsigned int w) { return bf2f((unsigned short)(w >> 16)); }

// ---------- CSR build ----------

__global__ __launch_bounds__(256) void k_count(const int* __restrict__ ei, int E, int N,
                                               int* __restrict__ deg) {
    int e = blockIdx.x * 256 + threadIdx.x;
    if (e >= E) return;
    int d = ei[E + e];
    if ((unsigned)d < (unsigned)N) atomicAdd(deg + d, 1);
}

__global__ __launch_bounds__(256) void k_blocksum(const int* __restrict__ deg, int N,
                                                  int* __restrict__ partial) {
    __shared__ int tmp[256];
    int t = threadIdx.x;
    int i = blockIdx.x * 256 + t;
    tmp[t] = (i < N) ? deg[i] : 0;
    __syncthreads();
    for (int off = 128; off > 0; off >>= 1) {
        if (t < off) tmp[t] += tmp[t + off];
        __syncthreads();
    }
    if (t == 0) partial[blockIdx.x] = tmp[0];
}

// single-block exclusive scan of partial[0..NB) -> offsets   (requires NB <= 1024)
__global__ __launch_bounds__(1024) void k_scanpartial(const int* __restrict__ partial, int NB,
                                                      int* __restrict__ offsets) {
    __shared__ int tmp[1024];
    int t = threadIdx.x;
    int v = (t < NB) ? partial[t] : 0;
    tmp[t] = v;
    __syncthreads();
    for (int off = 1; off < 1024; off <<= 1) {
        int a = (t >= off) ? tmp[t - off] : 0;
        __syncthreads();
        tmp[t] += a;
        __syncthreads();
    }
    if (t < NB) offsets[t] = tmp[t] - v;
}

__global__ __launch_bounds__(256) void k_scandeg(const int* __restrict__ deg, int N,
                                                 const int* __restrict__ offsets,
                                                 int* __restrict__ cursor) {
    __shared__ int tmp[256];
    int t = threadIdx.x;
    int i = blockIdx.x * 256 + t;
    int v = (i < N) ? deg[i] : 0;
    tmp[t] = v;
    __syncthreads();
    for (int off = 1; off < 256; off <<= 1) {
        int a = (t >= off) ? tmp[t - off] : 0;
        __syncthreads();
        tmp[t] += a;
        __syncthreads();
    }
    if (i < N) cursor[i] = offsets[blockIdx.x] + tmp[t] - v;
}

__global__ __launch_bounds__(256) void k_fill(const int* __restrict__ ei, int E, int N,
                                              int* __restrict__ cursor, int* __restrict__ adj) {
    int e = blockIdx.x * 256 + threadIdx.x;
    if (e >= E) return;
    int s = ei[e];
    int d = ei[E + e];
    if ((unsigned)s >= (unsigned)N || (unsigned)d >= (unsigned)N) return;
    int pos = atomicAdd(cursor + d, 1);   // cursor ends at row end = rowstart + deg
    if ((unsigned)pos < (unsigned)E) adj[pos] = s;
}

// ---------- pre1: z10 = x@W1[10] (bf16), r1 = x@Wr1[d_n]+b1 (bf16) ----------
// wave per 4 nodes; lane (u = lane>>5, o = lane&31) covers nodes {q+u, q+u+2}.
// x read as wave-uniform float4 broadcasts; W1[10] loads shared by all 4 nodes.
__global__ __launch_bounds__(256) void k_pre1(const float* __restrict__ x,
                                              const int* __restrict__ deg,
                                              const float* __restrict__ W1,
                                              const float* __restrict__ b1,
                                              const float* __restrict__ Wr1,
                                              unsigned short* __restrict__ z10,
                                              unsigned short* __restrict__ r1, int N) {
    int wq = (int)(((long long)blockIdx.x * 256 + threadIdx.x) >> 6);
    int q = wq * 4;
    if (q >= N) return;
    int lane = threadIdx.x & 63;
    int u = lane >> 5;
    int o = lane & 31;
    int n_a = q + u;
    int n_b = q + u + 2;
    int ca = (n_a < N) ? n_a : N - 1;
    int cb = (n_b < N) ? n_b : N - 1;
    int da = min(deg[ca], MAXDEG);
    int db = min(deg[cb], MAXDEG);
    const float* Wz  = W1  + (size_t)MAXDEG * (FIN * FHID) + o;
    const float* Wra = Wr1 + (size_t)da * (FIN * FHID) + o;
    const float* Wrb = Wr1 + (size_t)db * (FIN * FHID) + o;
    const float4* xa4 = (const float4*)(x + (size_t)ca * FIN);
    const float4* xb4 = (const float4*)(x + (size_t)cb * FIN);
    float za = 0.f, zb = 0.f, ra = 0.f, rb = 0.f;
#pragma unroll 4
    for (int f4 = 0; f4 < FIN / 4; ++f4) {
        float4 xa = xa4[f4];
        float4 xb = xb4[f4];
#pragma unroll
        for (int j = 0; j < 4; ++j) {
            int f = f4 * 4 + j;
            float xaj = (j == 0) ? xa.x : (j == 1) ? xa.y : (j == 2) ? xa.z : xa.w;
            float xbj = (j == 0) ? xb.x : (j == 1) ? xb.y : (j == 2) ? xb.z : xb.w;
            float wz = Wz[f * FHID];
            float wa = Wra[f * FHID];
            float wb = Wrb[f * FHID];
            za += xaj * wz;
            zb += xbj * wz;
            ra += xaj * wa;
            rb += xbj * wb;
        }
    }
    if (n_a < N) {
        z10[(size_t)n_a * FHID + o] = f2bf(za);
        r1[(size_t)n_a * FHID + o]  = f2bf(ra + b1[da * FHID + o]);
    }
    if (n_b < N) {
        z10[(size_t)n_b * FHID + o] = f2bf(zb);
        r1[(size_t)n_b * FHID + o]  = f2bf(rb + b1[db * FHID + o]);
    }
}

// ---------- layer1: deg>=10 fast path gathers bf16 z10 rows with high MLP ----------
// Index preload: one coalesced adj load covers <=64 neighbors; 8 groups x 8 lanes,
// lane loads ushort4 (8B) -> 64B row per group; all row loads issue up-front.
__global__ __launch_bounds__(256) void k_layer1b(const float* __restrict__ x,
                                                 const unsigned short* __restrict__ z10,
                                                 const unsigned short* __restrict__ r1,
                                                 const int* __restrict__ deg,
                                                 const int* __restrict__ cursor,
                                                 const int* __restrict__ adj,
                                                 const float* __restrict__ W1,
                                                 unsigned short* __restrict__ out1, int N) {
    int wave = (int)(((long long)blockIdx.x * 256 + threadIdx.x) >> 6);
    if (wave >= N) return;
    int n = wave;
    int lane = threadIdx.x & 63;
    int dg = deg[n];
    int e1 = cursor[n];
    int e0 = e1 - dg;
    if (dg >= MAXDEG) {
        int g = lane >> 3, l = lane & 7;
        int myk = e0 + lane;
        int sidx = (myk < e1) ? adj[myk] : 0;
        int cnt = min(dg, 64);
        float a0 = 0.f, a1 = 0.f, a2 = 0.f, a3 = 0.f;
        for (int i = 0; i * 8 < cnt; ++i) {
            int idx = i * 8 + g;
            int s = __shfl(sidx, idx);
            if (idx < cnt) {
                ushort4 uv = *(const ushort4*)(z10 + (size_t)s * FHID + l * 4);
                a0 += bf2f(uv.x); a1 += bf2f(uv.y); a2 += bf2f(uv.z); a3 += bf2f(uv.w);
            }
        }
        for (int k = e0 + 64 + g; k < e1; k += 8) {  // deg>64: essentially never
            int s = adj[k];
            ushort4 uv = *(const ushort4*)(z10 + (size_t)s * FHID + l * 4);
            a0 += bf2f(uv.x); a1 += bf2f(uv.y); a2 += bf2f(uv.z); a3 += bf2f(uv.w);
        }
#pragma unroll
        for (int m = 8; m <= 32; m <<= 1) {
            a0 += __shfl_xor(a0, m); a1 += __shfl_xor(a1, m);
            a2 += __shfl_xor(a2, m); a3 += __shfl_xor(a3, m);
        }
        if (lane < 8) {
            ushort4 rv = *(const ushort4*)(r1 + (size_t)n * FHID + l * 4);
            ushort4 w;
            w.x = f2bf(fmaxf(a0 + bf2f(rv.x), 0.f));
            w.y = f2bf(fmaxf(a1 + bf2f(rv.y), 0.f));
            w.z = f2bf(fmaxf(a2 + bf2f(rv.z), 0.f));
            w.w = f2bf(fmaxf(a3 + bf2f(rv.w), 0.f));
            *(ushort4*)(out1 + (size_t)n * FHID + l * 4) = w;
        }
    } else {
        // rare (~4% of nodes): gather raw fp32 x rows, matvec with this node's bucket
        float2 hs = make_float2(0.f, 0.f);
        for (int k = e0; k < e1; ++k) {
            int s = adj[k];
            float2 v = *(const float2*)(x + (size_t)s * FIN + lane * 2);
            hs.x += v.x; hs.y += v.y;
        }
        int o = lane & 31;
        const float* Wp = W1 + (size_t)dg * (FIN * FHID) + o;
        float acc = 0.f;
#pragma unroll
        for (int f = 0; f < FIN; ++f) {
            float hv = __shfl((f & 1) ? hs.y : hs.x, f >> 1);
            acc += hv * Wp[f * FHID];
        }
        if (lane < 32) {
            float rv = bf2f(r1[(size_t)n * FHID + o]);
            out1[(size_t)n * FHID + o] = f2bf(fmaxf(acc + rv, 0.f));
        }
    }
}

// ---------- pre2: p = y@W2[10] (bf16), r2 = y@Wr2[d_n]+b2 (bf16) ----------
// wave per 4 nodes; lane j covers all 64 output cols; W2[10] loads shared by 4 nodes.
__global__ __launch_bounds__(256) void k_pre2(const unsigned short* __restrict__ y,
                                              const int* __restrict__ deg,
                                              const float* __restrict__ W2,
                                              const float* __restrict__ b2,
                                              const float* __restrict__ Wr2,
                                              unsigned short* __restrict__ p,
                                              unsigned short* __restrict__ r2, int N) {
    int wq = (int)(((long long)blockIdx.x * 256 + threadIdx.x) >> 6);
    int q = wq * 4;
    if (q >= N) return;
    int j = threadIdx.x & 63;
    int n[4], d[4];
#pragma unroll
    for (int k = 0; k < 4; ++k) {
        n[k] = (q + k < N) ? q + k : N - 1;
        d[k] = min(deg[n[k]], MAXDEG);
    }
    const float* Wp = W2 + (size_t)MAXDEG * (FHID * FOUT) + j;
    const float* Wr[4];
    float accp[4], accr[4];
#pragma unroll
    for (int k = 0; k < 4; ++k) {
        Wr[k] = Wr2 + (size_t)d[k] * (FHID * FOUT) + j;
        accp[k] = 0.f;
        accr[k] = b2[d[k] * FOUT + j];
    }
#pragma unroll
    for (int c = 0; c < 4; ++c) {           // 8 features per chunk
        uint4 yc[4];
#pragma unroll
        for (int k = 0; k < 4; ++k)
            yc[k] = ((const uint4*)(y + (size_t)n[k] * FHID))[c];
#pragma unroll
        for (int m = 0; m < 8; ++m) {
            int f = c * 8 + m;
            float wv = Wp[f * FOUT];
            float yv[4];
#pragma unroll
            for (int k = 0; k < 4; ++k) {
                unsigned int word = (m >> 1 == 0) ? yc[k].x : (m >> 1 == 1) ? yc[k].y
                                   : (m >> 1 == 2) ? yc[k].z : yc[k].w;
                yv[k] = bf2f((unsigned short)((m & 1) ? (word >> 16) : (word & 0xffff)));
            }
#pragma unroll
            for (int k = 0; k < 4; ++k) {
                accp[k] += yv[k] * wv;
                accr[k] += yv[k] * Wr[k][f * FOUT];
            }
        }
    }
#pragma unroll
    for (int k = 0; k < 4; ++k) {
        if (q + k < N) {
            p[(size_t)n[k] * FOUT + j]  = f2bf(accp[k]);
            r2[(size_t)n[k] * FOUT + j] = f2bf(accr[k]);
        }
    }
}

// ---------- layer2: deg>=10 fast path gathers bf16 p rows (128B) with high MLP ----------
__global__ __launch_bounds__(256) void k_layer2b(const unsigned short* __restrict__ p,
                                                 const unsigned short* __restrict__ r2,
                                                 const unsigned short* __restrict__ y,
                                                 const int* __restrict__ deg,
                                                 const int* __restrict__ cursor,
                                                 const int* __restrict__ adj,
                                                 const float* __restrict__ W2,
                                                 float* __restrict__ out, int N) {
    int wave = (int)(((long long)blockIdx.x * 256 + threadIdx.x) >> 6);
    if (wave >= N) return;
    int n = wave;
    int lane = threadIdx.x & 63;
    int dg = deg[n];
    int e1 = cursor[n];
    int e0 = e1 - dg;
    if (dg >= MAXDEG) {
        int g = lane >> 3, l = lane & 7;
        int myk = e0 + lane;
        int sidx = (myk < e1) ? adj[myk] : 0;
        int cnt = min(dg, 64);
        float a[8];
#pragma unroll
        for (int m = 0; m < 8; ++m) a[m] = 0.f;
        for (int i = 0; i * 8 < cnt; ++i) {
            int idx = i * 8 + g;
            int s = __shfl(sidx, idx);
            if (idx < cnt) {
                uint4 uv = *(const uint4*)(p + (size_t)s * FOUT + l * 8);
                a[0] += bflo(uv.x); a[1] += bfhi(uv.x);
                a[2] += bflo(uv.y); a[3] += bfhi(uv.y);
                a[4] += bflo(uv.z); a[5] += bfhi(uv.z);
                a[6] += bflo(uv.w); a[7] += bfhi(uv.w);
            }
        }
        for (int k = e0 + 64 + g; k < e1; k += 8) {  // deg>64: essentially never
            int s = adj[k];
            uint4 uv = *(const uint4*)(p + (size_t)s * FOUT + l * 8);
            a[0] += bflo(uv.x); a[1] += bfhi(uv.x);
            a[2] += bflo(uv.y); a[3] += bfhi(uv.y);
            a[4] += bflo(uv.z); a[5] += bfhi(uv.z);
            a[6] += bflo(uv.w); a[7] += bfhi(uv.w);
        }
#pragma unroll
        for (int m = 8; m <= 32; m <<= 1) {
#pragma unroll
            for (int t = 0; t < 8; ++t) a[t] += __shfl_xor(a[t], m);
        }
        if (lane < 8) {
            uint4 rv = *(const uint4*)(r2 + (size_t)n * FOUT + l * 8);
            float4 o0, o1;
            o0.x = a[0] + bflo(rv.x); o0.y = a[1] + bfhi(rv.x);
            o0.z = a[2] + bflo(rv.y); o0.w = a[3] + bfhi(rv.y);
            o1.x = a[4] + bflo(rv.z); o1.y = a[5] + bfhi(rv.z);
            o1.z = a[6] + bflo(rv.w); o1.w = a[7] + bfhi(rv.w);
            float* op = out + (size_t)n * FOUT + l * 8;
            *(float4*)op = o0;
            *(float4*)(op + 4) = o1;
        }
    } else {
        // rare: gather bf16 y rows (4-way ILP), then 32->64 matvec; r2 has root+bias
        int g = lane >> 4, l = lane & 15;
        float2 h = make_float2(0.f, 0.f);
        for (int k = e0 + g; k < e1; k += 4) {
            int s = adj[k];
            ushort2 uv = *(const ushort2*)(y + (size_t)s * FHID + l * 2);
            h.x += bf2f(uv.x); h.y += bf2f(uv.y);
        }
        h.x += __shfl_xor(h.x, 16); h.y += __shfl_xor(h.y, 16);
        h.x += __shfl_xor(h.x, 32); h.y += __shfl_xor(h.y, 32);
        const float* Wp = W2 + (size_t)dg * (FHID * FOUT) + lane;
        float acc = bf2f(r2[(size_t)n * FOUT + lane]);
#pragma unroll
        for (int f = 0; f < FHID; ++f) {
            float hf = __shfl((f & 1) ? h.y : h.x, f >> 1);
            acc += hf * Wp[f * FOUT];
        }
        out[(size_t)n * FOUT + lane] = acc;
    }
}

extern "C" void kernel_launch(void* const* d_in, const int* in_sizes, int n_in,
                              void* d_out, int out_size, void* d_ws, size_t ws_size,
                              hipStream_t stream) {
    const float* x   = (const float*)d_in[0];
    const int*   ei  = (const int*)d_in[1];   // int32, [2, E] flat
    const float* W1  = (const float*)d_in[2];
    const float* b1  = (const float*)d_in[3];
    const float* Wr1 = (const float*)d_in[4];
    const float* W2  = (const float*)d_in[5];
    const float* b2  = (const float*)d_in[6];
    const float* Wr2 = (const float*)d_in[7];

    int N = in_sizes[0] / FIN;
    int E = in_sizes[1] / 2;
    int NB = (N + 255) / 256;

    char* ws = (char*)d_ws;
    size_t off = 0;
    auto alloc = [&](size_t bytes) {
        void* ptr = ws + off;
        off += (bytes + 511) / 512 * 512;
        return ptr;
    };
    int* deg              = (int*)alloc((size_t)N * sizeof(int));
    int* cursor           = (int*)alloc((size_t)N * sizeof(int));
    int* partial          = (int*)alloc((size_t)NB * sizeof(int));
    int* offsets          = (int*)alloc((size_t)NB * sizeof(int));
    int* adj              = (int*)alloc((size_t)E * sizeof(int));
    unsigned short* z10   = (unsigned short*)alloc((size_t)N * FHID * 2);
    unsigned short* r1    = (unsigned short*)alloc((size_t)N * FHID * 2);
    unsigned short* out1  = (unsigned short*)alloc((size_t)N * FHID * 2);
    unsigned short* p     = (unsigned short*)alloc((size_t)N * FOUT * 2);
    unsigned short* r2    = (unsigned short*)alloc((size_t)N * FOUT * 2);
    // total ~52 MB for N=100K, E=1.6M

    float* out = (float*)d_out;

    hipMemsetAsync(deg, 0, (size_t)N * sizeof(int), stream);

    int eb = (E + 255) / 256;
    k_count<<<eb, 256, 0, stream>>>(ei, E, N, deg);
    k_blocksum<<<NB, 256, 0, stream>>>(deg, N, partial);
    k_scanpartial<<<1, 1024, 0, stream>>>(partial, NB, offsets);
    k_scandeg<<<NB, 256, 0, stream>>>(deg, N, offsets, cursor);
    k_fill<<<eb, 256, 0, stream>>>(ei, E, N, cursor, adj);

    int nb_quad = (N + 15) / 16;  // wave per 4 nodes
    int nb_node = (N + 3) / 4;    // wave per node
    k_pre1<<<nb_quad, 256, 0, stream>>>(x, deg, W1, b1, Wr1, z10, r1, N);
    k_layer1b<<<nb_node, 256, 0, stream>>>(x, z10, r1, deg, cursor, adj, W1, out1, N);
    k_pre2<<<nb_quad, 256, 0, stream>>>(out1, deg, W2, b2, Wr2, p, r2, N);
    k_layer2b<<<nb_node, 256, 0, stream>>>(p, r2, out1, deg, cursor, adj, W2, out, N);
}